// Round 11
// baseline (96.796 us; speedup 1.0000x reference)
//
#include <hip/hip_runtime.h>
#include <math.h>

// One thread per TWO batch elements as a packed float2 (v_pk_* fp32).
// R11:
//  - incremental exponentials: E=exp(ch) kept as state, updated per iter by
//    E *= taylor4(-step) (|step| <= ~0.2 -> rel err <= 3e-6/iter).
//    Replaces 6 quarter-rate v_exp_f32 + premul with 15 packed fma/mul.
//  - s1 accumulated directly per lambda (drops K/KU finals, -3 ops/iter).
// Retains: cubic phi(u) Horner, batched product-reciprocal, clamped-rsqrt
// Adam, diagonal-Sym(Se)/Sym(Sa) fast path, dense fallback.

typedef float v2f __attribute__((ext_vector_type(2)));

__device__ __forceinline__ float frcp(float x)  { return __builtin_amdgcn_rcpf(x); }
__device__ __forceinline__ float fsqrt_(float x){ return __builtin_amdgcn_sqrtf(x); }
__device__ __forceinline__ float fexp2_(float x){ return __builtin_amdgcn_exp2f(x); }  // v_exp_f32 = 2^x
__device__ __forceinline__ float frsq_(float x) { return __builtin_amdgcn_rsqf(x); }
__device__ __forceinline__ float fexp(float x)  { return __expf(x); }

__device__ __forceinline__ v2f vrcp(v2f x){ v2f r; r.x = frcp(x.x); r.y = frcp(x.y); return r; }
__device__ __forceinline__ v2f vsqrt(v2f x){ v2f r; r.x = fsqrt_(x.x); r.y = fsqrt_(x.y); return r; }
__device__ __forceinline__ v2f vrsq(v2f x){ v2f r; r.x = frsq_(x.x); r.y = frsq_(x.y); return r; }
__device__ __forceinline__ v2f vexp(v2f x){ v2f r; r.x = fexp(x.x); r.y = fexp(x.y); return r; }
__device__ __forceinline__ v2f vexp_fast(v2f x){
    const v2f xs = x * 1.442695040888963f;
    v2f r; r.x = fexp2_(xs.x); r.y = fexp2_(xs.y); return r;
}
__device__ __forceinline__ v2f vminc(v2f x, float c){
    v2f r; r.x = fminf(x.x, c); r.y = fminf(x.y, c); return r;
}
__device__ __forceinline__ v2f bcast(float x){ v2f r; r.x = x; r.y = x; return r; }
// exp(-s) ~= 1 - s(1 - s(1/2 - s(1/6 - s/24))) : 4 packed fma
__device__ __forceinline__ v2f texpm(v2f s){
    v2f t = 0.16666667f - s * 0.041666667f;
    t = 0.5f - s * t;
    t = 1.0f - s * t;
    return 1.0f - s * t;
}

__global__ __launch_bounds__(64)
void pe_kernel(const float* __restrict__ X,      // (B,5,5)
               const float* __restrict__ Y,      // (B,5)
               const float* __restrict__ ch0p,   // (B,1,3)
               const float* __restrict__ pf,     // (14,)
               const float* __restrict__ x_a,    // (3,)
               const float* __restrict__ s_a_inv,// (3,3)
               const float* __restrict__ s_e_inv,// (5,5)
               const int*   __restrict__ n_iter, // (1,)
               float* __restrict__ out,          // (B,9)
               int B, int n0)                    // n0 = ceil(B/2)
{
    const int b = blockIdx.x * blockDim.x + threadIdx.x;
    if (b >= n0) return;

    const bool valid1 = (b + n0) < B;
    const int e0 = b;
    const int e1 = valid1 ? (b + n0) : b;

    const float lam[5] = {-0.275f, 0.025f, 0.5f, 0.7f, 1.15f};

    float pfv[14];
#pragma unroll
    for (int i = 0; i < 14; ++i) pfv[i] = pf[i];

    const float xa0 = x_a[0], xa1 = x_a[1], xa2 = x_a[2];

    float Sa[3][3];
#pragma unroll
    for (int i = 0; i < 3; ++i)
#pragma unroll
        for (int j = 0; j < 3; ++j)
            Sa[i][j] = 0.5f * (s_a_inv[i*3+j] + s_a_inv[j*3+i]);

    float Se[5][5];
#pragma unroll
    for (int i = 0; i < 5; ++i)
#pragma unroll
        for (int j = 0; j < 5; ++j)
            Se[i][j] = 0.5f * (s_e_inv[i*5+j] + s_e_inv[j*5+i]);

    // Wave-uniform structure check.
    bool diag = true;
#pragma unroll
    for (int i = 0; i < 5; ++i)
#pragma unroll
        for (int j = 0; j < 5; ++j)
            if (i != j && Se[i][j] != 0.0f) diag = false;
#pragma unroll
    for (int i = 0; i < 3; ++i)
#pragma unroll
        for (int j = 0; j < 3; ++j)
            if (i != j && Sa[i][j] != 0.0f) diag = false;

    const int T = n_iter[0];

    // Iteration-invariant optics constants (uniform).
    const float A0   = 0.0045f, Bb0 = 0.0012f;
    const float Anap = pfv[12] * 0.005f;
    const float Bnap = pfv[13] * 0.005f;
    const float c1   = pfv[7] * 0.089f;
    const float c2   = pfv[8] * 0.1245f;
    const float c22  = 2.0f * c2;
    float Aph[5], Acd[5], Bph[5];
#pragma unroll
    for (int l = 0; l < 5; ++l) {
        Aph[l] = pfv[0] * 0.05f * (1.0f + pfv[1] * 0.1f * lam[l] + pfv[2] * 0.01f);
        Acd[l] = pfv[5] * 0.1f * fexp(-pfv[6] * 1.7f * lam[l]);
        Bph[l] = pfv[3] * 0.001f * (1.0f + pfv[4] * 0.05f * lam[l]);
    }

    // Per-element iteration-invariant data, packed (elem0, elem1).
    v2f E[5], Yv[5], x3[5];
#pragma unroll
    for (int l = 0; l < 5; ++l) {
        const float Edir0 = X[e0*25 + l*5 + 0], Edir1 = X[e1*25 + l*5 + 0];
        const float Edif0 = X[e0*25 + l*5 + 1], Edif1 = X[e1*25 + l*5 + 1];
        x3[l].x = X[e0*25 + l*5 + 3];  x3[l].y = X[e1*25 + l*5 + 3];
        E[l].x  = (Edir0 + 0.5f * Edif0) * frcp(Edir0 + Edif0);
        E[l].y  = (Edir1 + 0.5f * Edif1) * frcp(Edir1 + Edif1);
        Yv[l].x = Y[e0*5 + l];  Yv[l].y = Y[e1*5 + l];
    }

    v2f ch[3], mm[3], vv[3];
#pragma unroll
    for (int k = 0; k < 3; ++k) {
        ch[k].x = ch0p[e0*3 + k];
        ch[k].y = ch0p[e1*3 + k];
        mm[k] = (v2f)0.0f;
        vv[k] = (v2f)0.0f;
    }

    float p1 = 1.0f, p2 = 1.0f;
    const float B1c = 0.9f,  oB1 = 1.0f - 0.9f;
    const float B2c = 0.999f, oB2 = 1.0f - 0.999f;
    const float LR = 0.02f, EPSc = 1e-8f;
    const float INV_EPS = 1e8f;

    if (diag) {
        // ---------- fast path: diagonal Sym(Se), Sym(Sa) ----------
        const float SaD0 = Sa[0][0], SaD1 = Sa[1][1], SaD2 = Sa[2][2];
        const float ABn  = Anap + Bnap;
        const float AB0  = A0 + Bb0;

        // Per-lambda broadcast constants + cubic coefficients of
        // phi(u) = (c1+2c2 u)((c1 u + c2 u^2) E2S - YES).
        v2f AB2[5], Bph2[5], Acd2[5], d3[5], d2[5], d1[5], d0[5];
        const float k3 = 2.0f * c2 * c2;
        const float k2 = 3.0f * c1 * c2;
        const float k1 = c1 * c1;
#pragma unroll
        for (int l = 0; l < 5; ++l) {
            AB2[l]  = bcast(Aph[l] + Bph[l]);
            Bph2[l] = bcast(Bph[l]);
            Acd2[l] = bcast(Acd[l]);
            const v2f E2S = (Se[l][l] * E[l]) * E[l];
            const v2f YES = (Se[l][l] * E[l]) * Yv[l];
            d3[l] = k3 * E2S;
            d2[l] = k2 * E2S;
            d1[l] = k1 * E2S - c22 * YES;
            d0[l] = -c1 * YES;
        }
        const v2f Bnapv = bcast(Bnap), ABnv = bcast(ABn);

        // Incremental exponential state.
        v2f Ee[3];
        Ee[0] = vexp_fast(ch[0]);
        Ee[1] = vexp_fast(ch[1]);
        Ee[2] = vexp_fast(ch[2]);

        for (int t = 0; t < T; ++t) {
            p1 *= B1c; p2 *= B2c;
            const float lrim = LR * frcp(1.0f - p1);   // LR/(1-b1^t)
            const float sqp2 = fsqrt_(1.0f - p2);      // sqrt(1-b2^t)

            const v2f chla = Ee[0];
            const v2f nap  = Ee[1];
            const v2f cdom = Ee[2];

            const v2f bt = Bb0 + Bnap * nap;
            const v2f ct = AB0 + ABn  * nap;

            // Stage s, bb per lambda.
            v2f sv[5], bbv[5];
#pragma unroll
            for (int l = 0; l < 5; ++l) {
                sv[l]  = AB2[l] * chla + (Acd2[l] * cdom + ct);
                bbv[l] = Bph2[l] * chla + bt;
            }

            // Batched reciprocal: 1/s_i = (prod_{j!=i}) * rcp(prod all).
            const v2f P1 = sv[0] * sv[1];
            const v2f P2 = P1 * sv[2];
            const v2f P3 = P2 * sv[3];
            const v2f Pa = P3 * sv[4];
            const v2f S3 = sv[4] * sv[3];
            const v2f S2 = S3 * sv[2];
            const v2f S1 = S2 * sv[1];
            const v2f rP = vrcp(Pa);
            v2f inv[5];
            inv[0] = S1 * rP;
            inv[1] = (sv[0] * S2) * rP;
            inv[2] = (P1 * S3) * rP;
            inv[3] = (P2 * sv[4]) * rP;
            inv[4] = P3 * rP;

            v2f s0p = (v2f)0.0f, s0m = (v2f)0.0f;
            v2f s1a = (v2f)0.0f, s1b = (v2f)0.0f;
            v2f s2a = (v2f)0.0f, s2b = (v2f)0.0f;
#pragma unroll
            for (int l = 0; l < 5; ++l) {
                const v2f u   = bbv[l] * inv[l];
                // phi(u) via Horner: 3 fma
                const v2f phi = ((d3[l] * u + d2[l]) * u + d1[l]) * u + d0[l];
                const v2f k   = inv[l] * phi;
                const v2f ku  = k * u;
                if ((l & 1) == 0) {
                    s1a += Bnapv * k;
                    s2a += Acd2[l] * ku;
                } else {
                    s1b += Bnapv * k;
                    s2b += Acd2[l] * ku;
                }
                s1a -= ABnv * ku;   // fold both halves of s1 contribution
                s0p += Bph2[l] * k;
                s0m += AB2[l]  * ku;
            }
            const v2f s0 = s0p - s0m;
            const v2f s1 = s1a + s1b;
            const v2f s2 = s2a + s2b;

            v2f gs[3];
            gs[0] = SaD0 * (ch[0] - xa0) + chla * s0;
            gs[1] = SaD1 * (ch[1] - xa1) + nap  * s1;
            gs[2] = SaD2 * (ch[2] - xa2) - cdom * s2;

#pragma unroll
            for (int k = 0; k < 3; ++k) {
                const v2f g = gs[k];
                mm[k] = B1c * mm[k] + oB1 * g;
                vv[k] = B2c * vv[k] + oB2 * (g * g);
                const v2f dinv = vminc(vrsq(vv[k]) * sqp2, INV_EPS);
                const v2f step = lrim * (mm[k] * dinv);
                ch[k] -= step;
                Ee[k] *= texpm(step);   // E *= exp(-step), 4th-order Taylor
            }
        }
    } else {
        // ---------- general path (dense Sym(Se)/Sym(Sa)) ----------
        for (int t = 0; t < T; ++t) {
            p1 *= B1c; p2 *= B2c;
            const float im   = frcp(1.0f - p1);
            const float sqiv = fsqrt_(frcp(1.0f - p2));
            const float lrim = LR * im;

            const v2f chla = vexp(ch[0]);
            const v2f nap  = vexp(ch[1]);
            const v2f cdom = vexp(ch[2]);

            const v2f d0 = ch[0] - xa0, d1 = ch[1] - xa1, d2 = ch[2] - xa2;
            v2f g0 = Sa[0][0]*d0 + Sa[0][1]*d1 + Sa[0][2]*d2;
            v2f g1 = Sa[1][0]*d0 + Sa[1][1]*d1 + Sa[1][2]*d2;
            v2f g2 = Sa[2][0]*d0 + Sa[2][1]*d1 + Sa[2][2]*d2;

            const v2f da1 = Anap * nap;
            const v2f db1 = Bnap * nap;

            v2f av[5], bv[5], wv[5], rv[5];
#pragma unroll
            for (int l = 0; l < 5; ++l) {
                const v2f da0 = Aph[l] * chla;
                const v2f db0 = Bph[l] * chla;
                const v2f da2 = Acd[l] * cdom;
                const v2f a   = A0  + da0 + da2 + da1;
                const v2f bb  = Bb0 + db0 + db1;
                const v2f inv_s = vrcp(a + bb);
                const v2f u     = bb * inv_s;
                const v2f rrs   = (c1 + c2 * u) * u;
                av[l] = a;
                bv[l] = bb;
                rv[l] = rrs * E[l] - Yv[l];
                wv[l] = (c1 + c22 * u) * E[l] * inv_s * inv_s;
            }

            v2f s0 = (v2f)0.0f, s1 = (v2f)0.0f, s2 = (v2f)0.0f;
#pragma unroll
            for (int i = 0; i < 5; ++i) {
                const v2f q = Se[i][0]*rv[0] + Se[i][1]*rv[1] + Se[i][2]*rv[2]
                            + Se[i][3]*rv[3] + Se[i][4]*rv[4];
                const v2f h = wv[i] * q;
                s0 += h * (Bph[i] * av[i] - Aph[i] * bv[i]);
                s1 += h * (Bnap   * av[i] - Anap   * bv[i]);
                s2 += h * (Acd[i] * bv[i]);
            }
            g0 += chla * s0;
            g1 += nap  * s1;
            g2 -= cdom * s2;

            const v2f gs[3] = {g0, g1, g2};
#pragma unroll
            for (int k = 0; k < 3; ++k) {
                const v2f g = gs[k];
                mm[k] = B1c * mm[k] + oB1 * g;
                vv[k] = B2c * vv[k] + oB2 * (g * g);
                const v2f den = vsqrt(vv[k]) * sqiv + EPSc;
                ch[k] -= (lrim * mm[k]) * vrcp(den);
            }
        }
    }

    // Epilogue
    const float kdscale = pfv[9] * 0.9f + pfv[10] * 0.1f;
    const float lam3[3] = {0.025f, 0.5f, 1.15f};

    const v2f chla = vexp(ch[0]);
    const v2f nap  = vexp(ch[1]);
    const v2f cdom = vexp(ch[2]);

#pragma unroll
    for (int ee = 0; ee < 2; ++ee) {
        if (ee == 1 && !valid1) break;
        const int e = ee ? e1 : e0;
        const float chl = ee ? chla.y : chla.x;
        const float np  = ee ? nap.y  : nap.x;
        const float cd  = ee ? cdom.y : cdom.x;

        float o[9];
        o[0] = ee ? ch[0].y : ch[0].x;
#pragma unroll
        for (int l = 0; l < 5; ++l) {
            const float a  = A0  + Aph[l]*chl + Acd[l]*cd + Anap*np;
            const float bb = Bb0 + Bph[l]*chl + Bnap*np;
            const float xx = ee ? x3[l].y : x3[l].x;
            const float sig = frcp(1.0f + fexp(-xx));
            const float mu  = 0.5f + 0.5f * sig;
            o[1 + l] = (a + bb) * frcp(mu) * kdscale;
        }
#pragma unroll
        for (int j = 0; j < 3; ++j) {
            const float bph = pfv[3] * 0.001f * (1.0f + pfv[4] * 0.05f * lam3[j]);
            o[6 + j] = pfv[11] * (bph * chl + Bnap * np);
        }
#pragma unroll
        for (int i = 0; i < 9; ++i) out[e*9 + i] = o[i];
    }
}

extern "C" void kernel_launch(void* const* d_in, const int* in_sizes, int n_in,
                              void* d_out, int out_size, void* d_ws, size_t ws_size,
                              hipStream_t stream) {
    const float* X   = (const float*)d_in[0];
    const float* Y   = (const float*)d_in[1];
    const float* ch0 = (const float*)d_in[2];
    const float* pf  = (const float*)d_in[3];
    const float* xa  = (const float*)d_in[4];
    const float* sa  = (const float*)d_in[5];
    const float* se  = (const float*)d_in[6];
    const int*   ni  = (const int*)d_in[7];
    float* out = (float*)d_out;

    const int B  = in_sizes[0] / 25;
    const int n0 = (B + 1) / 2;
    const int block = 64;
    const int grid = (n0 + block - 1) / block;
    hipLaunchKernelGGL(pe_kernel, dim3(grid), dim3(block), 0, stream,
                       X, Y, ch0, pf, xa, sa, se, ni, out, B, n0);
}

// Round 12
// 94.716 us; speedup vs baseline: 1.0220x; 1.0220x over previous
//
#include <hip/hip_runtime.h>
#include <math.h>

// One thread per TWO batch elements as a packed float2 (v_pk_* fp32).
// R12 = R10 restored (best verified config; R11's incremental-exp regressed:
// it added 5 dependent levels to the loop-carried ch->exp recurrence, which
// dominates at 1 wave/SIMD).
//   - cubic phi(u) Horner collapse of the per-lambda response chain
//   - batched product-reciprocal for the 5 per-lambda divisions
//   - clamped-rsqrt Adam denominator; exp via log2e premul + v_exp_f32
//   - diagonal-Sym(Se)/Sym(Sa) wave-uniform fast path; dense fallback

typedef float v2f __attribute__((ext_vector_type(2)));

__device__ __forceinline__ float frcp(float x)  { return __builtin_amdgcn_rcpf(x); }
__device__ __forceinline__ float fsqrt_(float x){ return __builtin_amdgcn_sqrtf(x); }
__device__ __forceinline__ float fexp2_(float x){ return __builtin_amdgcn_exp2f(x); }  // v_exp_f32 = 2^x
__device__ __forceinline__ float frsq_(float x) { return __builtin_amdgcn_rsqf(x); }
__device__ __forceinline__ float fexp(float x)  { return __expf(x); }

__device__ __forceinline__ v2f vrcp(v2f x){ v2f r; r.x = frcp(x.x); r.y = frcp(x.y); return r; }
__device__ __forceinline__ v2f vsqrt(v2f x){ v2f r; r.x = fsqrt_(x.x); r.y = fsqrt_(x.y); return r; }
__device__ __forceinline__ v2f vrsq(v2f x){ v2f r; r.x = frsq_(x.x); r.y = frsq_(x.y); return r; }
__device__ __forceinline__ v2f vexp(v2f x){ v2f r; r.x = fexp(x.x); r.y = fexp(x.y); return r; }
__device__ __forceinline__ v2f vexp_fast(v2f x){
    const v2f xs = x * 1.442695040888963f;
    v2f r; r.x = fexp2_(xs.x); r.y = fexp2_(xs.y); return r;
}
__device__ __forceinline__ v2f vminc(v2f x, float c){
    v2f r; r.x = fminf(x.x, c); r.y = fminf(x.y, c); return r;
}
__device__ __forceinline__ v2f bcast(float x){ v2f r; r.x = x; r.y = x; return r; }

__global__ __launch_bounds__(64)
void pe_kernel(const float* __restrict__ X,      // (B,5,5)
               const float* __restrict__ Y,      // (B,5)
               const float* __restrict__ ch0p,   // (B,1,3)
               const float* __restrict__ pf,     // (14,)
               const float* __restrict__ x_a,    // (3,)
               const float* __restrict__ s_a_inv,// (3,3)
               const float* __restrict__ s_e_inv,// (5,5)
               const int*   __restrict__ n_iter, // (1,)
               float* __restrict__ out,          // (B,9)
               int B, int n0)                    // n0 = ceil(B/2)
{
    const int b = blockIdx.x * blockDim.x + threadIdx.x;
    if (b >= n0) return;

    const bool valid1 = (b + n0) < B;
    const int e0 = b;
    const int e1 = valid1 ? (b + n0) : b;

    const float lam[5] = {-0.275f, 0.025f, 0.5f, 0.7f, 1.15f};

    float pfv[14];
#pragma unroll
    for (int i = 0; i < 14; ++i) pfv[i] = pf[i];

    const float xa0 = x_a[0], xa1 = x_a[1], xa2 = x_a[2];

    float Sa[3][3];
#pragma unroll
    for (int i = 0; i < 3; ++i)
#pragma unroll
        for (int j = 0; j < 3; ++j)
            Sa[i][j] = 0.5f * (s_a_inv[i*3+j] + s_a_inv[j*3+i]);

    float Se[5][5];
#pragma unroll
    for (int i = 0; i < 5; ++i)
#pragma unroll
        for (int j = 0; j < 5; ++j)
            Se[i][j] = 0.5f * (s_e_inv[i*5+j] + s_e_inv[j*5+i]);

    // Wave-uniform structure check.
    bool diag = true;
#pragma unroll
    for (int i = 0; i < 5; ++i)
#pragma unroll
        for (int j = 0; j < 5; ++j)
            if (i != j && Se[i][j] != 0.0f) diag = false;
#pragma unroll
    for (int i = 0; i < 3; ++i)
#pragma unroll
        for (int j = 0; j < 3; ++j)
            if (i != j && Sa[i][j] != 0.0f) diag = false;

    const int T = n_iter[0];

    // Iteration-invariant optics constants (uniform).
    const float A0   = 0.0045f, Bb0 = 0.0012f;
    const float Anap = pfv[12] * 0.005f;
    const float Bnap = pfv[13] * 0.005f;
    const float c1   = pfv[7] * 0.089f;
    const float c2   = pfv[8] * 0.1245f;
    const float c22  = 2.0f * c2;
    float Aph[5], Acd[5], Bph[5];
#pragma unroll
    for (int l = 0; l < 5; ++l) {
        Aph[l] = pfv[0] * 0.05f * (1.0f + pfv[1] * 0.1f * lam[l] + pfv[2] * 0.01f);
        Acd[l] = pfv[5] * 0.1f * fexp(-pfv[6] * 1.7f * lam[l]);
        Bph[l] = pfv[3] * 0.001f * (1.0f + pfv[4] * 0.05f * lam[l]);
    }

    // Per-element iteration-invariant data, packed (elem0, elem1).
    v2f E[5], Yv[5], x3[5];
#pragma unroll
    for (int l = 0; l < 5; ++l) {
        const float Edir0 = X[e0*25 + l*5 + 0], Edir1 = X[e1*25 + l*5 + 0];
        const float Edif0 = X[e0*25 + l*5 + 1], Edif1 = X[e1*25 + l*5 + 1];
        x3[l].x = X[e0*25 + l*5 + 3];  x3[l].y = X[e1*25 + l*5 + 3];
        E[l].x  = (Edir0 + 0.5f * Edif0) * frcp(Edir0 + Edif0);
        E[l].y  = (Edir1 + 0.5f * Edif1) * frcp(Edir1 + Edif1);
        Yv[l].x = Y[e0*5 + l];  Yv[l].y = Y[e1*5 + l];
    }

    v2f ch[3], mm[3], vv[3];
#pragma unroll
    for (int k = 0; k < 3; ++k) {
        ch[k].x = ch0p[e0*3 + k];
        ch[k].y = ch0p[e1*3 + k];
        mm[k] = (v2f)0.0f;
        vv[k] = (v2f)0.0f;
    }

    float p1 = 1.0f, p2 = 1.0f;
    const float B1c = 0.9f,  oB1 = 1.0f - 0.9f;
    const float B2c = 0.999f, oB2 = 1.0f - 0.999f;
    const float LR = 0.02f, EPSc = 1e-8f;
    const float INV_EPS = 1e8f;

    if (diag) {
        // ---------- fast path: diagonal Sym(Se), Sym(Sa) ----------
        const float SaD0 = Sa[0][0], SaD1 = Sa[1][1], SaD2 = Sa[2][2];
        const float ABn  = Anap + Bnap;
        const float AB0  = A0 + Bb0;

        // Per-lambda broadcast constants + cubic coefficients of
        // phi(u) = (c1+2c2 u)((c1 u + c2 u^2) E2S - YES).
        v2f AB2[5], Bph2[5], Acd2[5], d3[5], d2[5], d1[5], d0[5];
        const float k3 = 2.0f * c2 * c2;
        const float k2 = 3.0f * c1 * c2;
        const float k1 = c1 * c1;
#pragma unroll
        for (int l = 0; l < 5; ++l) {
            AB2[l]  = bcast(Aph[l] + Bph[l]);
            Bph2[l] = bcast(Bph[l]);
            Acd2[l] = bcast(Acd[l]);
            const v2f E2S = (Se[l][l] * E[l]) * E[l];
            const v2f YES = (Se[l][l] * E[l]) * Yv[l];
            d3[l] = k3 * E2S;
            d2[l] = k2 * E2S;
            d1[l] = k1 * E2S - c22 * YES;
            d0[l] = -c1 * YES;
        }
        const v2f Bnapv = bcast(Bnap), ABnv = bcast(ABn);

        for (int t = 0; t < T; ++t) {
            p1 *= B1c; p2 *= B2c;
            const float lrim = LR * frcp(1.0f - p1);   // LR/(1-b1^t)
            const float sqp2 = fsqrt_(1.0f - p2);      // sqrt(1-b2^t)

            const v2f chla = vexp_fast(ch[0]);
            const v2f nap  = vexp_fast(ch[1]);
            const v2f cdom = vexp_fast(ch[2]);

            const v2f bt = Bb0 + Bnap * nap;
            const v2f ct = AB0 + ABn  * nap;

            // Stage s, bb per lambda.
            v2f sv[5], bbv[5];
#pragma unroll
            for (int l = 0; l < 5; ++l) {
                sv[l]  = AB2[l] * chla + (Acd2[l] * cdom + ct);
                bbv[l] = Bph2[l] * chla + bt;
            }

            // Batched reciprocal: 1/s_i = (prod_{j!=i}) * rcp(prod all).
            const v2f P1 = sv[0] * sv[1];
            const v2f P2 = P1 * sv[2];
            const v2f P3 = P2 * sv[3];
            const v2f Pa = P3 * sv[4];
            const v2f S3 = sv[4] * sv[3];
            const v2f S2 = S3 * sv[2];
            const v2f S1 = S2 * sv[1];
            const v2f rP = vrcp(Pa);
            v2f inv[5];
            inv[0] = S1 * rP;
            inv[1] = (sv[0] * S2) * rP;
            inv[2] = (P1 * S3) * rP;
            inv[3] = (P2 * sv[4]) * rP;
            inv[4] = P3 * rP;

            v2f Ka = (v2f)0.0f, Kb = (v2f)0.0f;
            v2f KUa = (v2f)0.0f, KUb = (v2f)0.0f;
            v2f s0p = (v2f)0.0f, s0m = (v2f)0.0f;
            v2f s2a = (v2f)0.0f, s2b = (v2f)0.0f;
#pragma unroll
            for (int l = 0; l < 5; ++l) {
                const v2f u   = bbv[l] * inv[l];
                // phi(u) via Horner: 3 fma
                const v2f phi = ((d3[l] * u + d2[l]) * u + d1[l]) * u + d0[l];
                const v2f k   = inv[l] * phi;
                const v2f ku  = k * u;
                if ((l & 1) == 0) {
                    Ka  += k;
                    KUa += ku;
                    s2a += Acd2[l] * ku;
                } else {
                    Kb  += k;
                    KUb += ku;
                    s2b += Acd2[l] * ku;
                }
                s0p += Bph2[l] * k;
                s0m += AB2[l]  * ku;
            }
            const v2f K  = Ka + Kb;
            const v2f KU = KUa + KUb;
            const v2f s0 = s0p - s0m;
            const v2f s2 = s2a + s2b;
            const v2f s1 = Bnapv * K - ABnv * KU;

            v2f gs[3];
            gs[0] = SaD0 * (ch[0] - xa0) + chla * s0;
            gs[1] = SaD1 * (ch[1] - xa1) + nap  * s1;
            gs[2] = SaD2 * (ch[2] - xa2) - cdom * s2;

#pragma unroll
            for (int k = 0; k < 3; ++k) {
                const v2f g = gs[k];
                mm[k] = B1c * mm[k] + oB1 * g;
                vv[k] = B2c * vv[k] + oB2 * (g * g);
                const v2f dinv = vminc(vrsq(vv[k]) * sqp2, INV_EPS);
                ch[k] -= lrim * (mm[k] * dinv);
            }
        }
    } else {
        // ---------- general path (dense Sym(Se)/Sym(Sa)) ----------
        for (int t = 0; t < T; ++t) {
            p1 *= B1c; p2 *= B2c;
            const float im   = frcp(1.0f - p1);
            const float sqiv = fsqrt_(frcp(1.0f - p2));
            const float lrim = LR * im;

            const v2f chla = vexp(ch[0]);
            const v2f nap  = vexp(ch[1]);
            const v2f cdom = vexp(ch[2]);

            const v2f d0 = ch[0] - xa0, d1 = ch[1] - xa1, d2 = ch[2] - xa2;
            v2f g0 = Sa[0][0]*d0 + Sa[0][1]*d1 + Sa[0][2]*d2;
            v2f g1 = Sa[1][0]*d0 + Sa[1][1]*d1 + Sa[1][2]*d2;
            v2f g2 = Sa[2][0]*d0 + Sa[2][1]*d1 + Sa[2][2]*d2;

            const v2f da1 = Anap * nap;
            const v2f db1 = Bnap * nap;

            v2f av[5], bv[5], wv[5], rv[5];
#pragma unroll
            for (int l = 0; l < 5; ++l) {
                const v2f da0 = Aph[l] * chla;
                const v2f db0 = Bph[l] * chla;
                const v2f da2 = Acd[l] * cdom;
                const v2f a   = A0  + da0 + da2 + da1;
                const v2f bb  = Bb0 + db0 + db1;
                const v2f inv_s = vrcp(a + bb);
                const v2f u     = bb * inv_s;
                const v2f rrs   = (c1 + c2 * u) * u;
                av[l] = a;
                bv[l] = bb;
                rv[l] = rrs * E[l] - Yv[l];
                wv[l] = (c1 + c22 * u) * E[l] * inv_s * inv_s;
            }

            v2f s0 = (v2f)0.0f, s1 = (v2f)0.0f, s2 = (v2f)0.0f;
#pragma unroll
            for (int i = 0; i < 5; ++i) {
                const v2f q = Se[i][0]*rv[0] + Se[i][1]*rv[1] + Se[i][2]*rv[2]
                            + Se[i][3]*rv[3] + Se[i][4]*rv[4];
                const v2f h = wv[i] * q;
                s0 += h * (Bph[i] * av[i] - Aph[i] * bv[i]);
                s1 += h * (Bnap   * av[i] - Anap   * bv[i]);
                s2 += h * (Acd[i] * bv[i]);
            }
            g0 += chla * s0;
            g1 += nap  * s1;
            g2 -= cdom * s2;

            const v2f gs[3] = {g0, g1, g2};
#pragma unroll
            for (int k = 0; k < 3; ++k) {
                const v2f g = gs[k];
                mm[k] = B1c * mm[k] + oB1 * g;
                vv[k] = B2c * vv[k] + oB2 * (g * g);
                const v2f den = vsqrt(vv[k]) * sqiv + EPSc;
                ch[k] -= (lrim * mm[k]) * vrcp(den);
            }
        }
    }

    // Epilogue
    const float kdscale = pfv[9] * 0.9f + pfv[10] * 0.1f;
    const float lam3[3] = {0.025f, 0.5f, 1.15f};

    const v2f chla = vexp(ch[0]);
    const v2f nap  = vexp(ch[1]);
    const v2f cdom = vexp(ch[2]);

#pragma unroll
    for (int ee = 0; ee < 2; ++ee) {
        if (ee == 1 && !valid1) break;
        const int e = ee ? e1 : e0;
        const float chl = ee ? chla.y : chla.x;
        const float np  = ee ? nap.y  : nap.x;
        const float cd  = ee ? cdom.y : cdom.x;

        float o[9];
        o[0] = ee ? ch[0].y : ch[0].x;
#pragma unroll
        for (int l = 0; l < 5; ++l) {
            const float a  = A0  + Aph[l]*chl + Acd[l]*cd + Anap*np;
            const float bb = Bb0 + Bph[l]*chl + Bnap*np;
            const float xx = ee ? x3[l].y : x3[l].x;
            const float sig = frcp(1.0f + fexp(-xx));
            const float mu  = 0.5f + 0.5f * sig;
            o[1 + l] = (a + bb) * frcp(mu) * kdscale;
        }
#pragma unroll
        for (int j = 0; j < 3; ++j) {
            const float bph = pfv[3] * 0.001f * (1.0f + pfv[4] * 0.05f * lam3[j]);
            o[6 + j] = pfv[11] * (bph * chl + Bnap * np);
        }
#pragma unroll
        for (int i = 0; i < 9; ++i) out[e*9 + i] = o[i];
    }
}

extern "C" void kernel_launch(void* const* d_in, const int* in_sizes, int n_in,
                              void* d_out, int out_size, void* d_ws, size_t ws_size,
                              hipStream_t stream) {
    const float* X   = (const float*)d_in[0];
    const float* Y   = (const float*)d_in[1];
    const float* ch0 = (const float*)d_in[2];
    const float* pf  = (const float*)d_in[3];
    const float* xa  = (const float*)d_in[4];
    const float* sa  = (const float*)d_in[5];
    const float* se  = (const float*)d_in[6];
    const int*   ni  = (const int*)d_in[7];
    float* out = (float*)d_out;

    const int B  = in_sizes[0] / 25;
    const int n0 = (B + 1) / 2;
    const int block = 64;
    const int grid = (n0 + block - 1) / block;
    hipLaunchKernelGGL(pe_kernel, dim3(grid), dim3(block), 0, stream,
                       X, Y, ch0, pf, xa, sa, se, ni, out, B, n0);
}